// Round 1
// baseline (502.227 us; speedup 1.0000x reference)
//
#include <hip/hip_runtime.h>
#include <math.h>

// ---------------------------------------------------------------------------
// RFA_SPDConv_Fourier_SDI: with K=1,c=1 the softmax over axis=2 (size 1) is
// identically 1.0 -> the entire "gw" weight branch is dead. Only the gf
// branch matters:
//   sp   = silu(bn(spdconv(x)))              (16,512,512) zero pad r/c 511
//   F    = rfft2(sp)                          keep ky 0..511, kx 0..255
//   t[4] = {lowRe, lowIm, highRe, highIm}    (16,256,256) each
//   y_c  = conv3x3(t_c) + sdi_b ; p_c = cumprod_b(y_c)
//   f    = silu(bn_fuse(sum_c fuse_w[c]*p_c))
//   f2   = relu(bn_gen(f))
//   out[b,o,i,j] = f2[b,i,j] * w_final[o]    (16,64,256,256)
// ---------------------------------------------------------------------------

#define PI_F 3.14159265358979323846f

__device__ __forceinline__ int brev9(int x) { return (int)(__brev((unsigned)x) >> 23); }

// ---------------- Stage A: spdconv + bn + silu -> sp (16,512,512) ----------
__global__ void spd_kernel(const float* __restrict__ x,
                           const float* __restrict__ w4,
                           const float* __restrict__ g1,
                           const float* __restrict__ b1,
                           float* __restrict__ sp) {
    int idx = blockIdx.x * 256 + threadIdx.x;     // over 16*512*512
    int j = idx & 511;
    int i = (idx >> 9) & 511;
    int b = idx >> 18;
    float v = 0.f;
    if (i < 511 && j < 511) {
        const float* row0 = x + ((size_t)b * 1022 + 2 * i) * 1022 + 2 * j;
        const float* row1 = row0 + 1022;
        float2 e = *(const float2*)row0;   // even row: cols 2j, 2j+1
        float2 o = *(const float2*)row1;   // odd  row
        // concat order: [::2,::2], [1::2,::2], [::2,1::2], [1::2,1::2]
        v = w4[0] * e.x + w4[1] * o.x + w4[2] * e.y + w4[3] * o.y;
        float scale = g1[0] * rsqrtf(1.0f + 1e-5f);
        v = v * scale + b1[0];
        v = v / (1.0f + expf(-v));         // silu
    }
    sp[idx] = v;
}

// ---------------- Stage B: row FFTs (real 512) -> R[b][y][kx<256] ----------
// wave-per-FFT; 4 rows per 256-thread block; radix-2 DIT in LDS.
__global__ void fft_rows(const float* __restrict__ sp,
                         float* __restrict__ Rre,
                         float* __restrict__ Rim) {
    __shared__ float s_re[4][512];
    __shared__ float s_im[4][512];
    __shared__ float tw_c[256];
    __shared__ float tw_s[256];
    int t = threadIdx.x;
    {
        float ang = -2.0f * PI_F * (float)t / 512.0f;
        float sn, cs;
        sincosf(ang, &sn, &cs);
        tw_c[t] = cs; tw_s[t] = sn;
    }
    int w = t >> 6;
    int l = t & 63;
    int row = blockIdx.x * 4 + w;          // 0..8191  (b*512 + y)
    const float* src = sp + (size_t)row * 512;
    float* re = s_re[w];
    float* im = s_im[w];
    for (int n = 0; n < 8; n++) {
        int p = n * 64 + l;
        int q = brev9(p);
        re[q] = src[p];
        im[q] = 0.f;
    }
    __syncthreads();
    for (int s = 1; s <= 9; s++) {
        int half = 1 << (s - 1);
        int m = half << 1;
        for (int n = 0; n < 4; n++) {
            int bt  = n * 64 + l;
            int grp = bt >> (s - 1);
            int pos = bt & (half - 1);
            int i0  = grp * m + pos;
            int i1  = i0 + half;
            int ti  = pos << (9 - s);
            float cs = tw_c[ti], sn = tw_s[ti];
            float ur = re[i0], ui = im[i0];
            float vr = re[i1], vi = im[i1];
            float tr = vr * cs - vi * sn;
            float tii = vr * sn + vi * cs;
            re[i0] = ur + tr;  im[i0] = ui + tii;
            re[i1] = ur - tr;  im[i1] = ui - tii;
        }
        __syncthreads();
    }
    float* pr = Rre + (size_t)row * 256;
    float* pi = Rim + (size_t)row * 256;
    for (int n = 0; n < 4; n++) {
        int k = n * 64 + l;
        pr[k] = re[k];
        pi[k] = im[k];
    }
}

// ---------------- Stage C: column FFTs (complex 512) -> t planes -----------
// t layout: [c][b][ky][kx], c-plane stride 16*256*256
__global__ void fft_cols(const float* __restrict__ Rre,
                         const float* __restrict__ Rim,
                         float* __restrict__ tpl) {
    __shared__ float s_re[4][512];
    __shared__ float s_im[4][512];
    __shared__ float tw_c[256];
    __shared__ float tw_s[256];
    int t = threadIdx.x;
    {
        float ang = -2.0f * PI_F * (float)t / 512.0f;
        float sn, cs;
        sincosf(ang, &sn, &cs);
        tw_c[t] = cs; tw_s[t] = sn;
    }
    int w = t >> 6;
    int l = t & 63;
    int col = blockIdx.x * 4 + w;          // 0..4095 (b*256 + kx)
    int b  = col >> 8;
    int kx = col & 255;
    const float* pr = Rre + (size_t)b * 512 * 256 + kx;
    const float* pi = Rim + (size_t)b * 512 * 256 + kx;
    float* re = s_re[w];
    float* im = s_im[w];
    for (int n = 0; n < 8; n++) {
        int y = n * 64 + l;
        int q = brev9(y);
        re[q] = pr[(size_t)y * 256];
        im[q] = pi[(size_t)y * 256];
    }
    __syncthreads();
    for (int s = 1; s <= 9; s++) {
        int half = 1 << (s - 1);
        int m = half << 1;
        for (int n = 0; n < 4; n++) {
            int bt  = n * 64 + l;
            int grp = bt >> (s - 1);
            int pos = bt & (half - 1);
            int i0  = grp * m + pos;
            int i1  = i0 + half;
            int ti  = pos << (9 - s);
            float cs = tw_c[ti], sn = tw_s[ti];
            float ur = re[i0], ui = im[i0];
            float vr = re[i1], vi = im[i1];
            float tr = vr * cs - vi * sn;
            float tii = vr * sn + vi * cs;
            re[i0] = ur + tr;  im[i0] = ui + tii;
            re[i1] = ur - tr;  im[i1] = ui - tii;
        }
        __syncthreads();
    }
    const size_t plane = (size_t)16 * 256 * 256;
    float* t0 = tpl + ((size_t)b * 256) * 256 + kx;
    for (int n = 0; n < 4; n++) {
        int ky = n * 64 + l;
        size_t off = (size_t)ky * 256;
        t0[off]             = re[ky];        // low.real
        t0[plane + off]     = im[ky];        // low.imag
        t0[2 * plane + off] = re[ky + 256];  // high.real
        t0[3 * plane + off] = im[ky + 256];  // high.imag
    }
}

// ------- Stage D1: conv3x3+bias, cumprod over b, fuse+bn+silu+bn+relu ------
__global__ void sdi_fuse(const float* __restrict__ tpl,
                         const float* __restrict__ sdiw,
                         const float* __restrict__ sdib,
                         const float* __restrict__ fw,
                         const float* __restrict__ fg,
                         const float* __restrict__ fb,
                         const float* __restrict__ gg,
                         const float* __restrict__ gb,
                         float* __restrict__ feat2) {
    int j = threadIdx.x;   // 0..255
    int i = blockIdx.x;    // 0..255
    float w9[9];
#pragma unroll
    for (int k = 0; k < 9; k++) w9[k] = sdiw[k];
    float bias = sdib[0];
    float fwv[4] = {fw[0], fw[1], fw[2], fw[3]};
    float inv = rsqrtf(1.0f + 1e-5f);
    float fscale = fg[0] * inv, fbias = fb[0];
    float gscale = gg[0] * inv, gbias = gb[0];
    float p[4] = {1.f, 1.f, 1.f, 1.f};
    const size_t plane = (size_t)16 * 256 * 256;
    for (int b = 0; b < 16; b++) {
        float f = 0.f;
#pragma unroll
        for (int c = 0; c < 4; c++) {
            const float* base = tpl + c * plane + ((size_t)b * 256) * 256;
            float acc = bias;
#pragma unroll
            for (int di = 0; di < 3; di++) {
                int ii = i + di - 1;
                if (ii < 0 || ii > 255) continue;
                const float* rowp = base + (size_t)ii * 256;
#pragma unroll
                for (int dj = 0; dj < 3; dj++) {
                    int jj = j + dj - 1;
                    if (jj < 0 || jj > 255) continue;
                    acc += w9[di * 3 + dj] * rowp[jj];
                }
            }
            p[c] *= acc;
            f += fwv[c] * p[c];
        }
        float bnv = f * fscale + fbias;
        float feat = bnv / (1.0f + expf(-bnv));   // silu
        float f2 = feat * gscale + gbias;
        f2 = fmaxf(f2, 0.f);                      // relu
        feat2[((size_t)b * 256 + i) * 256 + j] = f2;
    }
}

// ---------------- Stage D2: out[b,o,i,j] = feat2[b,i,j] * wf[o] ------------
__global__ void expand_out(const float* __restrict__ feat2,
                           const float* __restrict__ wf,
                           float* __restrict__ out) {
    int tid = blockIdx.x * 256 + threadIdx.x;   // 0..262143 = (b, i, j4)
    int j4 = tid & 63;
    int i  = (tid >> 6) & 255;
    int b  = tid >> 14;
    const float4 v = *(const float4*)(feat2 + (((size_t)b * 256 + i) * 256 + j4 * 4));
    float* obase = out + (size_t)b * 64 * 65536 + (size_t)i * 256 + j4 * 4;
#pragma unroll
    for (int o = 0; o < 64; o++) {
        float s = wf[o];
        float4 r = make_float4(v.x * s, v.y * s, v.z * s, v.w * s);
        *(float4*)(obase + (size_t)o * 65536) = r;
    }
}

extern "C" void kernel_launch(void* const* d_in, const int* in_sizes, int n_in,
                              void* d_out, int out_size, void* d_ws, size_t ws_size,
                              hipStream_t stream) {
    const float* x     = (const float*)d_in[0];
    // gw branch (d_in[1..8]) is dead: softmax over singleton axis == 1
    const float* w_spd = (const float*)d_in[9];
    const float* bng   = (const float*)d_in[10];
    const float* bnb   = (const float*)d_in[11];
    const float* sdiw  = (const float*)d_in[12];
    const float* sdib  = (const float*)d_in[13];
    const float* fw    = (const float*)d_in[14];
    const float* fg    = (const float*)d_in[15];
    const float* fb    = (const float*)d_in[16];
    const float* gg    = (const float*)d_in[17];
    const float* gb    = (const float*)d_in[18];
    const float* wf    = (const float*)d_in[19];
    float* out = (float*)d_out;

    // workspace layout (32 MB):
    //   sp   [0, 16MB)            16*512*512 floats   (aliased later by tpl)
    //   Rre  [16MB, 24MB)         16*512*256
    //   Rim  [24MB, 32MB)         16*512*256
    //   tpl  aliases sp           4*16*256*256
    //   feat2 aliases Rre         16*256*256
    float* sp    = (float*)d_ws;
    float* Rre   = sp + (size_t)16 * 512 * 512;
    float* Rim   = Rre + (size_t)16 * 512 * 256;
    float* tpl   = sp;
    float* feat2 = Rre;

    spd_kernel<<<dim3(16384), dim3(256), 0, stream>>>(x, w_spd, bng, bnb, sp);
    fft_rows  <<<dim3(2048),  dim3(256), 0, stream>>>(sp, Rre, Rim);
    fft_cols  <<<dim3(1024),  dim3(256), 0, stream>>>(Rre, Rim, tpl);
    sdi_fuse  <<<dim3(256),   dim3(256), 0, stream>>>(tpl, sdiw, sdib, fw, fg, fb, gg, gb, feat2);
    expand_out<<<dim3(1024),  dim3(256), 0, stream>>>(feat2, wf, out);
}

// Round 2
// 414.164 us; speedup vs baseline: 1.2126x; 1.2126x over previous
//
#include <hip/hip_runtime.h>
#include <math.h>

// ---------------------------------------------------------------------------
// K=1,c=1 -> softmax over singleton axis == 1 -> gw branch dead. Pipeline:
//   sp   = silu(bn(spdconv(x)))            (16,512,512), row/col 511 zero
//   F    = fft2(sp) ; keep ky 0..511, kx 0..255
//   tpl  = {lowRe,lowIm,highRe,highIm}     4 planes of (16,256,256)
//   y_c  = conv3x3(tpl_c)+sdi_b ; p_c = cumprod_b(y_c)
//   feat2= relu(bn_gen(silu(bn_fuse(sum_c fuse_w[c]*p_c))))
//   out[b,o,i,j] = feat2[b,i,j]*w_final[o] (16,64,256,256)
//
// Stage layout (ws = 32 MiB, all sub-buffers 16 MiB):
//   S1 fft_rows_spd : x -> RT[b][kx][y] (float2)      RT  = ws[0,16M)
//   S2 fft_cols     : RT -> tpl planes                tpl = ws[16M,32M)
//   S3 conv_y       : tpl -> y[c][b][i][j]            y   = ws[0,16M)  (RT dead)
//   S4 cum_fuse     : y -> feat2[b][i][j]             feat2 = ws[16M,20M) (tpl dead)
//   S5 expand       : feat2 -> out
// ---------------------------------------------------------------------------

#define PI_F 3.14159265358979323846f

__device__ __forceinline__ int brev9(int x) { return (int)(__brev((unsigned)x) >> 23); }

// Per-wave radix-2 DIT 512-pt FFT over one LDS row (complex float2).
// Input must be pre-scattered in bit-reversed order. Block-wide barriers.
__device__ __forceinline__ void fft512_lds(float2* row, const float* twc,
                                           const float* tws, int l) {
    for (int s = 1; s <= 9; s++) {
        int half = 1 << (s - 1);
        int m = half << 1;
#pragma unroll
        for (int n = 0; n < 4; n++) {
            int bt  = n * 64 + l;
            int grp = bt >> (s - 1);
            int pos = bt & (half - 1);
            int i0  = grp * m + pos;
            int i1  = i0 + half;
            int ti  = pos << (9 - s);
            float cs = twc[ti], sn = tws[ti];
            float2 u = row[i0], v = row[i1];
            float tr  = v.x * cs - v.y * sn;
            float tim = v.x * sn + v.y * cs;
            row[i0] = make_float2(u.x + tr,  u.y + tim);
            row[i1] = make_float2(u.x - tr,  u.y - tim);
        }
        __syncthreads();
    }
}

// ---- S1: spdconv (fused) + row FFTs; writes transposed RT[b][kx<256][y] ----
// 1024 blocks x 512 threads; block = 8 consecutive rows (one b).
__global__ __launch_bounds__(512) void fft_rows_spd(
        const float* __restrict__ x, const float* __restrict__ w4,
        const float* __restrict__ g1, const float* __restrict__ b1,
        float2* __restrict__ RT) {
    __shared__ float2 s[8][513];
    __shared__ float twc[256];
    __shared__ float tws[256];
    int t = threadIdx.x;
    if (t < 256) {
        float ang = -2.0f * PI_F * (float)t / 512.0f;
        float sn, cs; sincosf(ang, &sn, &cs);
        twc[t] = cs; tws[t] = sn;
    }
    int w = t >> 6, l = t & 63;
    int row = blockIdx.x * 8 + w;        // b*512 + y
    int b = row >> 9, yy = row & 511;
    float w0 = w4[0], w1 = w4[1], w2 = w4[2], w3 = w4[3];
    float scale = g1[0] * rsqrtf(1.0f + 1e-5f);
    float bias  = b1[0];
#pragma unroll
    for (int n = 0; n < 8; n++) {
        int p = n * 64 + l;
        float v = 0.f;
        if (yy < 511 && p < 511) {
            const float* r0 = x + ((size_t)b * 1022 + 2 * yy) * 1022 + 2 * p;
            float2 e = *(const float2*)r0;
            float2 o = *(const float2*)(r0 + 1022);
            v = w0 * e.x + w1 * o.x + w2 * e.y + w3 * o.y;
            v = v * scale + bias;
            v = v / (1.0f + expf(-v));
        }
        s[w][brev9(p)] = make_float2(v, 0.f);
    }
    __syncthreads();
    fft512_lds(s[w], twc, tws, l);
    // transposed write: thread t -> k = t>>1 (0..255), sub = t&1 (4 y each)
    int k = t >> 1, sub = t & 1;
    int y0 = (blockIdx.x & 63) * 8;           // 64 blocks per b
    float2* dst = RT + ((size_t)(b * 256 + k)) * 512 + y0 + sub * 4;
#pragma unroll
    for (int r = 0; r < 4; r++) dst[r] = s[sub * 4 + r][k];
}

// ---- S2: column FFTs; reads RT coalesced, writes 4 planes [c][b][ky][kx] ---
// 512 blocks x 512 threads; block = 8 consecutive kx (one b).
__global__ __launch_bounds__(512) void fft_cols_k(
        const float2* __restrict__ RT, float* __restrict__ tpl) {
    __shared__ float2 s[8][513];
    __shared__ float twc[256];
    __shared__ float tws[256];
    int t = threadIdx.x;
    if (t < 256) {
        float ang = -2.0f * PI_F * (float)t / 512.0f;
        float sn, cs; sincosf(ang, &sn, &cs);
        twc[t] = cs; tws[t] = sn;
    }
    int w = t >> 6, l = t & 63;
    int b = blockIdx.x >> 5;                  // 32 blocks per b
    int kx0 = (blockIdx.x & 31) * 8;
    const float2* src = RT + ((size_t)(b * 256 + kx0 + w)) * 512;
#pragma unroll
    for (int n = 0; n < 8; n++) {
        int yv = n * 64 + l;
        s[w][brev9(yv)] = src[yv];
    }
    __syncthreads();
    fft512_lds(s[w], twc, tws, l);
    const size_t plane = (size_t)16 * 256 * 256;
    int kx_off = t & 7;
    int kyg = t >> 3;                          // 0..63
#pragma unroll
    for (int p = 0; p < 4; p++) {
        int ky = p * 64 + kyg;
        float2 lo = s[kx_off][ky];
        float2 hi = s[kx_off][ky + 256];
        size_t off = ((size_t)(b * 256 + ky)) * 256 + kx0 + kx_off;
        tpl[off]             = lo.x;
        tpl[plane + off]     = lo.y;
        tpl[2 * plane + off] = hi.x;
        tpl[3 * plane + off] = hi.y;
    }
}

// ---- S3: y[c][b][i][j] = conv3x3(tpl[c][b]) + sdi_b ------------------------
__global__ void conv_y_k(const float* __restrict__ tpl,
                         const float* __restrict__ sdiw,
                         const float* __restrict__ sdib,
                         float* __restrict__ y) {
    int idx = blockIdx.x * 256 + threadIdx.x;   // 4*16*256*256 elements
    int j = idx & 255, i = (idx >> 8) & 255;
    const float* base = tpl + ((size_t)(idx >> 16)) * 65536;
    float acc = sdib[0];
    float w9[9];
#pragma unroll
    for (int k = 0; k < 9; k++) w9[k] = sdiw[k];
#pragma unroll
    for (int di = 0; di < 3; di++) {
        int ii = i + di - 1;
        if (ii < 0 || ii > 255) continue;
        const float* rowp = base + (size_t)ii * 256;
#pragma unroll
        for (int dj = 0; dj < 3; dj++) {
            int jj = j + dj - 1;
            if (jj < 0 || jj > 255) continue;
            acc += w9[di * 3 + dj] * rowp[jj];
        }
    }
    y[idx] = acc;
}

// ---- S4: cumprod over b + fuse 1x1 + bn + silu + bn + relu -> feat2 --------
__global__ void cum_fuse_k(const float* __restrict__ y,
                           const float* __restrict__ fw,
                           const float* __restrict__ fg,
                           const float* __restrict__ fb,
                           const float* __restrict__ gg,
                           const float* __restrict__ gb,
                           float* __restrict__ feat2) {
    int pix = blockIdx.x * 256 + threadIdx.x;   // 65536 pixels
    float v[16][4];
#pragma unroll
    for (int b = 0; b < 16; b++)
#pragma unroll
        for (int c = 0; c < 4; c++)
            v[b][c] = y[((size_t)(c * 16 + b)) * 65536 + pix];
    float inv = rsqrtf(1.0f + 1e-5f);
    float fscale = fg[0] * inv, fbias = fb[0];
    float gscale = gg[0] * inv, gbias = gb[0];
    float fw0 = fw[0], fw1 = fw[1], fw2 = fw[2], fw3 = fw[3];
    float p0 = 1.f, p1 = 1.f, p2 = 1.f, p3 = 1.f;
#pragma unroll
    for (int b = 0; b < 16; b++) {
        p0 *= v[b][0]; p1 *= v[b][1]; p2 *= v[b][2]; p3 *= v[b][3];
        float f = fw0 * p0 + fw1 * p1 + fw2 * p2 + fw3 * p3;
        float bnv = f * fscale + fbias;
        float feat = bnv / (1.0f + expf(-bnv));
        float f2 = feat * gscale + gbias;
        f2 = fmaxf(f2, 0.f);
        feat2[(size_t)b * 65536 + pix] = f2;
    }
}

// ---- S5: out[b,o,i,j] = feat2[b,i,j] * wf[o] -------------------------------
__global__ void expand_out(const float* __restrict__ feat2,
                           const float* __restrict__ wf,
                           float* __restrict__ out) {
    int tid = blockIdx.x * 256 + threadIdx.x;   // (b, i, j4)
    int j4 = tid & 63;
    int i  = (tid >> 6) & 255;
    int b  = tid >> 14;
    const float4 v = *(const float4*)(feat2 + (((size_t)b * 256 + i) * 256 + j4 * 4));
    float* obase = out + (size_t)b * 64 * 65536 + (size_t)i * 256 + j4 * 4;
#pragma unroll
    for (int o = 0; o < 64; o++) {
        float sC = wf[o];
        float4 r = make_float4(v.x * sC, v.y * sC, v.z * sC, v.w * sC);
        *(float4*)(obase + (size_t)o * 65536) = r;
    }
}

extern "C" void kernel_launch(void* const* d_in, const int* in_sizes, int n_in,
                              void* d_out, int out_size, void* d_ws, size_t ws_size,
                              hipStream_t stream) {
    const float* x    = (const float*)d_in[0];
    const float* wspd = (const float*)d_in[9];
    const float* bng  = (const float*)d_in[10];
    const float* bnb  = (const float*)d_in[11];
    const float* sdiw = (const float*)d_in[12];
    const float* sdib = (const float*)d_in[13];
    const float* fw   = (const float*)d_in[14];
    const float* fg   = (const float*)d_in[15];
    const float* fb   = (const float*)d_in[16];
    const float* gg   = (const float*)d_in[17];
    const float* gb   = (const float*)d_in[18];
    const float* wf   = (const float*)d_in[19];
    float* out = (float*)d_out;

    // 32 MiB workspace, recycled:
    float2* RT    = (float2*)d_ws;                       // [0, 16M)
    float*  tpl   = (float*)d_ws + (size_t)4 * 1024 * 1024; // [16M, 32M)
    float*  y     = (float*)d_ws;                        // alias RT (dead)
    float*  feat2 = tpl;                                 // alias tpl (dead)

    fft_rows_spd<<<dim3(1024),  dim3(512), 0, stream>>>(x, wspd, bng, bnb, RT);
    fft_cols_k  <<<dim3(512),   dim3(512), 0, stream>>>(RT, tpl);
    conv_y_k    <<<dim3(16384), dim3(256), 0, stream>>>(tpl, sdiw, sdib, y);
    cum_fuse_k  <<<dim3(256),   dim3(256), 0, stream>>>(y, fw, fg, fb, gg, gb, feat2);
    expand_out  <<<dim3(1024),  dim3(256), 0, stream>>>(feat2, wf, out);
}

// Round 3
// 399.972 us; speedup vs baseline: 1.2557x; 1.0355x over previous
//
#include <hip/hip_runtime.h>
#include <math.h>

// ---------------------------------------------------------------------------
// K=1,c=1 -> softmax over singleton axis == 1 -> gw branch dead. Pipeline:
//   sp   = silu(bn(spdconv(x)))            (16,512,512), row/col 511 zero
//   F    = fft2(sp) ; keep ky 0..511, kx 0..255
//   tpl  = {lowRe,lowIm,highRe,highIm}     4 planes of (16,256,256)
//   y_c  = conv3x3(tpl_c)+sdi_b ; p_c = cumprod_b(y_c)
//   feat2= relu(bn_gen(silu(bn_fuse(sum_c fuse_w[c]*p_c))))
//   out[b,o,i,j] = feat2[b,i,j]*w_final[o] (16,64,256,256)
//
// FFTs: radix-8 register FFT (512 = 8*8*8), 1 wave per FFT, 8 FFTs/block.
//   3x DFT8 in registers + 2 LDS exchanges + twiddle chains.
//   Thread T ends holding X[T + 64*brev3(m)] in reg m.
// ---------------------------------------------------------------------------

#define PI_F 3.14159265358979323846f

struct cpx { float re, im; };
__device__ __forceinline__ cpx cadd(cpx a, cpx b){ return {a.re+b.re, a.im+b.im}; }
__device__ __forceinline__ cpx csub(cpx a, cpx b){ return {a.re-b.re, a.im-b.im}; }
__device__ __forceinline__ cpx cmul(cpx a, cpx b){ return {a.re*b.re - a.im*b.im, a.re*b.im + a.im*b.re}; }
__device__ __forceinline__ cpx cnegi(cpx a){ return {a.im, -a.re}; }   // a * (-i)

// DFT8, decimation-in-frequency: reg m -> X[brev3(m)], brev3 = {0,4,2,6,1,5,3,7}
__device__ __forceinline__ void dft8_dif(cpx* a) {
    const float C = 0.70710678118654752440f;
    cpx t0=cadd(a[0],a[4]), t1=cadd(a[1],a[5]), t2=cadd(a[2],a[6]), t3=cadd(a[3],a[7]);
    cpx s0=csub(a[0],a[4]), s1=csub(a[1],a[5]), s2=csub(a[2],a[6]), s3=csub(a[3],a[7]);
    s1 = (cpx){ C*(s1.re + s1.im), C*(s1.im - s1.re) };   // * W8^1
    s2 = cnegi(s2);                                        // * W8^2
    s3 = (cpx){ C*(s3.im - s3.re), -C*(s3.re + s3.im) };   // * W8^3
    cpx u0=cadd(t0,t2), u1=cadd(t1,t3), u2=csub(t0,t2), u3=cnegi(csub(t1,t3));
    cpx v0=cadd(s0,s2), v1=cadd(s1,s3), v2=csub(s0,s2), v3=cnegi(csub(s1,s3));
    a[0]=cadd(u0,u1); a[1]=csub(u0,u1); a[2]=cadd(u2,u3); a[3]=csub(u2,u3);
    a[4]=cadd(v0,v1); a[5]=csub(v0,v1); a[6]=cadd(v2,v3); a[7]=csub(v2,v3);
}

// a[m] *= p^{brev3(m)}
__device__ __forceinline__ void twiddle_brev(cpx* a, cpx p) {
    cpx w = p;
    a[4] = cmul(a[4], w); w = cmul(w, p);   // p^1 -> brev3(4)=1
    a[2] = cmul(a[2], w); w = cmul(w, p);   // p^2
    a[6] = cmul(a[6], w); w = cmul(w, p);   // p^3
    a[1] = cmul(a[1], w); w = cmul(w, p);   // p^4
    a[5] = cmul(a[5], w); w = cmul(w, p);   // p^5
    a[3] = cmul(a[3], w); w = cmul(w, p);   // p^6
    a[7] = cmul(a[7], w);                   // p^7
}

// 512-pt FFT. a[m] in: x[t + 64*m]. out: a[m] = X[t + 64*brev3(m)].
// bR/bI: per-wave scratch, 576 floats each. 4 __syncthreads inside.
__device__ __forceinline__ void fft512_r8(cpx* a, float* bR, float* bI, int t) {
    float sn, cs;
    dft8_dif(a);
    sincosf(-2.0f * PI_F * (float)t / 512.0f, &sn, &cs);
    twiddle_brev(a, (cpx){cs, sn});
    // exchange 1: row = k0 (stride 69), col = t
    bR[0*69 + t] = a[0].re; bI[0*69 + t] = a[0].im;
    bR[4*69 + t] = a[1].re; bI[4*69 + t] = a[1].im;
    bR[2*69 + t] = a[2].re; bI[2*69 + t] = a[2].im;
    bR[6*69 + t] = a[3].re; bI[6*69 + t] = a[3].im;
    bR[1*69 + t] = a[4].re; bI[1*69 + t] = a[4].im;
    bR[5*69 + t] = a[5].re; bI[5*69 + t] = a[5].im;
    bR[3*69 + t] = a[6].re; bI[3*69 + t] = a[6].im;
    bR[7*69 + t] = a[7].re; bI[7*69 + t] = a[7].im;
    __syncthreads();
    int k0 = t & 7, t0 = t >> 3;
    cpx b[8];
#pragma unroll
    for (int i = 0; i < 8; i++) {
        b[i].re = bR[k0*69 + t0 + 8*i];
        b[i].im = bI[k0*69 + t0 + 8*i];
    }
    __syncthreads();
    dft8_dif(b);
    sincosf(-2.0f * PI_F * (float)t0 / 64.0f, &sn, &cs);
    twiddle_brev(b, (cpx){cs, sn});
    // exchange 2: row = j0*8 + k0 (stride 9), col = t0
    bR[(0*8 + k0)*9 + t0] = b[0].re; bI[(0*8 + k0)*9 + t0] = b[0].im;
    bR[(4*8 + k0)*9 + t0] = b[1].re; bI[(4*8 + k0)*9 + t0] = b[1].im;
    bR[(2*8 + k0)*9 + t0] = b[2].re; bI[(2*8 + k0)*9 + t0] = b[2].im;
    bR[(6*8 + k0)*9 + t0] = b[3].re; bI[(6*8 + k0)*9 + t0] = b[3].im;
    bR[(1*8 + k0)*9 + t0] = b[4].re; bI[(1*8 + k0)*9 + t0] = b[4].im;
    bR[(5*8 + k0)*9 + t0] = b[5].re; bI[(5*8 + k0)*9 + t0] = b[5].im;
    bR[(3*8 + k0)*9 + t0] = b[6].re; bI[(3*8 + k0)*9 + t0] = b[6].im;
    bR[(7*8 + k0)*9 + t0] = b[7].re; bI[(7*8 + k0)*9 + t0] = b[7].im;
    __syncthreads();
    int rowb = ((t >> 3) * 8 + (t & 7)) * 9;   // (j0n*8 + k0n)*9, k_low = T
#pragma unroll
    for (int i = 0; i < 8; i++) {
        a[i].re = bR[rowb + i];
        a[i].im = bI[rowb + i];
    }
    __syncthreads();   // scratch free for reuse after this
    dft8_dif(a);
}

// ---- S1: spdconv fused + row FFT; RT[b][kx<256][y] (float2), 64B stores ----
__global__ __launch_bounds__(512) void fft_rows_spd8(
        const float* __restrict__ x, const float* __restrict__ w4,
        const float* __restrict__ g1, const float* __restrict__ b1,
        float2* __restrict__ RT) {
    __shared__ __align__(16) float pool[9216];
    int tid = threadIdx.x;
    int w = tid >> 6, t = tid & 63;
    float* bR = pool + w * 1152;
    float* bI = bR + 576;
    int row = blockIdx.x * 8 + w;        // b*512 + y
    int b = row >> 9, yy = row & 511;
    float w0 = w4[0], w1 = w4[1], w2c = w4[2], w3 = w4[3];
    float scale = g1[0] * rsqrtf(1.f + 1e-5f);
    float bias  = b1[0];
    cpx a[8];
#pragma unroll
    for (int m = 0; m < 8; m++) {
        int p = t + 64 * m;
        float v = 0.f;
        if (yy < 511 && p < 511) {
            const float* r0 = x + ((size_t)b * 1022 + 2 * yy) * 1022 + 2 * p;
            float2 e = *(const float2*)r0;
            float2 o = *(const float2*)(r0 + 1022);
            v = w0 * e.x + w1 * o.x + w2c * e.y + w3 * o.y;
            v = v * scale + bias;
            v = v / (1.f + expf(-v));
        }
        a[m] = (cpx){v, 0.f};
    }
    fft512_r8(a, bR, bI, t);
    // keep k = t + 64*brev3(m) < 256 -> m in {0,4,2,6}
    float2* tile = (float2*)pool;        // [256][pad 9] float2 = 18 KB
    tile[(t +   0) * 9 + w] = make_float2(a[0].re, a[0].im);
    tile[(t +  64) * 9 + w] = make_float2(a[4].re, a[4].im);
    tile[(t + 128) * 9 + w] = make_float2(a[2].re, a[2].im);
    tile[(t + 192) * 9 + w] = make_float2(a[6].re, a[6].im);
    __syncthreads();
    int y0 = (blockIdx.x & 63) * 8;      // 64 blocks per b
    float2* dst = RT + (size_t)(b * 256) * 512 + y0;
#pragma unroll
    for (int r = 0; r < 4; r++) {
        int e = tid + 512 * r;           // 0..2047
        int k = e >> 3, ww = e & 7;
        dst[(size_t)k * 512 + ww] = tile[k * 9 + ww];
    }
}

// ---- S2: column FFT; reads RT coalesced; tpl planes [c][b][ky][kx] --------
__global__ __launch_bounds__(512) void fft_cols8(
        const float2* __restrict__ RT, float* __restrict__ tpl) {
    __shared__ __align__(16) float pool[9216];
    int tid = threadIdx.x;
    int w = tid >> 6, t = tid & 63;
    float* bR = pool + w * 1152;
    float* bI = bR + 576;
    int b = blockIdx.x >> 5;             // 32 blocks per b
    int kx0 = (blockIdx.x & 31) * 8;
    const float2* src = RT + (size_t)(b * 256 + kx0 + w) * 512;
    cpx a[8];
#pragma unroll
    for (int m = 0; m < 8; m++) {
        float2 v = src[t + 64 * m];
        a[m] = (cpx){v.x, v.y};
    }
    fft512_r8(a, bR, bI, t);
    float2* tile = (float2*)pool;        // [512][pad 9] float2 = 36,864 B
    tile[(t +   0) * 9 + w] = make_float2(a[0].re, a[0].im);
    tile[(t +  64) * 9 + w] = make_float2(a[4].re, a[4].im);
    tile[(t + 128) * 9 + w] = make_float2(a[2].re, a[2].im);
    tile[(t + 192) * 9 + w] = make_float2(a[6].re, a[6].im);
    tile[(t + 256) * 9 + w] = make_float2(a[1].re, a[1].im);
    tile[(t + 320) * 9 + w] = make_float2(a[5].re, a[5].im);
    tile[(t + 384) * 9 + w] = make_float2(a[3].re, a[3].im);
    tile[(t + 448) * 9 + w] = make_float2(a[7].re, a[7].im);
    __syncthreads();
    const size_t P = (size_t)16 * 256 * 256;
#pragma unroll
    for (int r = 0; r < 8; r++) {
        int e = tid + 512 * r;           // 0..4095
        int ky = e >> 3, ww = e & 7;
        float2 v = tile[ky * 9 + ww];
        if (ky < 256) {
            size_t idx = (size_t)(b * 256 + ky) * 256 + kx0 + ww;
            tpl[idx]     = v.x;          // low.real
            tpl[P + idx] = v.y;          // low.imag
        } else {
            size_t idx = (size_t)(b * 256 + (ky - 256)) * 256 + kx0 + ww;
            tpl[2*P + idx] = v.x;        // high.real
            tpl[3*P + idx] = v.y;        // high.imag
        }
    }
}

// ---- S3: y[c][b][i][j] = conv3x3(tpl[c][b]) + sdi_b ------------------------
__global__ void conv_y_k(const float* __restrict__ tpl,
                         const float* __restrict__ sdiw,
                         const float* __restrict__ sdib,
                         float* __restrict__ y) {
    int idx = blockIdx.x * 256 + threadIdx.x;   // 4*16*256*256
    int j = idx & 255, i = (idx >> 8) & 255;
    const float* base = tpl + ((size_t)(idx >> 16)) * 65536;
    float acc = sdib[0];
    float w9[9];
#pragma unroll
    for (int k = 0; k < 9; k++) w9[k] = sdiw[k];
#pragma unroll
    for (int di = 0; di < 3; di++) {
        int ii = i + di - 1;
        if (ii < 0 || ii > 255) continue;
        const float* rowp = base + (size_t)ii * 256;
#pragma unroll
        for (int dj = 0; dj < 3; dj++) {
            int jj = j + dj - 1;
            if (jj < 0 || jj > 255) continue;
            acc += w9[di * 3 + dj] * rowp[jj];
        }
    }
    y[idx] = acc;
}

// ---- S4: cumprod + fuse + bn/silu/bn/relu + broadcast*w_final -> out -------
__global__ __launch_bounds__(256) void cum_expand(
        const float* __restrict__ y,
        const float* __restrict__ fw, const float* __restrict__ fg,
        const float* __restrict__ fb, const float* __restrict__ gg,
        const float* __restrict__ gb, const float* __restrict__ wf,
        float* __restrict__ out) {
    int og = blockIdx.x & 1;                       // o-group of 32
    int pix = (blockIdx.x >> 1) * 256 + threadIdx.x;
    float v[16][4];
#pragma unroll
    for (int b = 0; b < 16; b++)
#pragma unroll
        for (int c = 0; c < 4; c++)
            v[b][c] = y[((size_t)(c * 16 + b)) * 65536 + pix];
    float inv = rsqrtf(1.f + 1e-5f);
    float fscale = fg[0] * inv, fbias = fb[0];
    float gscale = gg[0] * inv, gbias = gb[0];
    float fw0 = fw[0], fw1 = fw[1], fw2 = fw[2], fw3 = fw[3];
    float f2[16];
    float p0 = 1.f, p1 = 1.f, p2 = 1.f, p3 = 1.f;
#pragma unroll
    for (int b = 0; b < 16; b++) {
        p0 *= v[b][0]; p1 *= v[b][1]; p2 *= v[b][2]; p3 *= v[b][3];
        float f = fw0 * p0 + fw1 * p1 + fw2 * p2 + fw3 * p3;
        float bn = f * fscale + fbias;
        float ft = bn / (1.f + expf(-bn));
        float g = ft * gscale + gbias;
        f2[b] = fmaxf(g, 0.f);
    }
    for (int oo = 0; oo < 32; oo++) {
        int o = og * 32 + oo;
        float s = wf[o];
#pragma unroll
        for (int b = 0; b < 16; b++)
            out[((size_t)(b * 64 + o)) * 65536 + pix] = f2[b] * s;
    }
}

extern "C" void kernel_launch(void* const* d_in, const int* in_sizes, int n_in,
                              void* d_out, int out_size, void* d_ws, size_t ws_size,
                              hipStream_t stream) {
    const float* x    = (const float*)d_in[0];
    const float* wspd = (const float*)d_in[9];
    const float* bng  = (const float*)d_in[10];
    const float* bnb  = (const float*)d_in[11];
    const float* sdiw = (const float*)d_in[12];
    const float* sdib = (const float*)d_in[13];
    const float* fw   = (const float*)d_in[14];
    const float* fg   = (const float*)d_in[15];
    const float* fb   = (const float*)d_in[16];
    const float* gg   = (const float*)d_in[17];
    const float* gb   = (const float*)d_in[18];
    const float* wf   = (const float*)d_in[19];
    float* out = (float*)d_out;

    // 32 MiB workspace, recycled:
    float2* RT  = (float2*)d_ws;                          // [0, 16M)
    float*  tpl = (float*)d_ws + (size_t)4 * 1024 * 1024; // [16M, 32M)
    float*  y   = (float*)d_ws;                           // alias RT (dead)

    fft_rows_spd8<<<dim3(1024),  dim3(512), 0, stream>>>(x, wspd, bng, bnb, RT);
    fft_cols8    <<<dim3(512),   dim3(512), 0, stream>>>(RT, tpl);
    conv_y_k     <<<dim3(16384), dim3(256), 0, stream>>>(tpl, sdiw, sdib, y);
    cum_expand   <<<dim3(512),   dim3(256), 0, stream>>>(y, fw, fg, fb, gg, gb, wf, out);
}